// Round 2
// baseline (867.587 us; speedup 1.0000x reference)
//
#include <hip/hip_runtime.h>
#include <hip/hip_bf16.h>

#define N_NODES 100000
#define N_EDGES 1600000
#define DIM 128
#define C_OUT 64
#define NB_SCAN 49   // ceil(N_NODES / 2048)

static __device__ __forceinline__ float4 ld4(const float* p){ return *reinterpret_cast<const float4*>(p); }
static __device__ __forceinline__ void st4(float* p, float4 v){ *reinterpret_cast<float4*>(p) = v; }

// ---------------- transpose WA [128][N] -> WAt [N][128] ----------------
__global__ __launch_bounds__(256) void k_transpose(const float* __restrict__ WA, float* __restrict__ WAt){
  __shared__ float t[32][33];
  int n0 = blockIdx.x*32, d0 = blockIdx.y*32;
  int tx = threadIdx.x & 31, ty = threadIdx.x >> 5;   // 32 x 8
  #pragma unroll
  for (int i = 0; i < 32; i += 8){
    int d = d0 + ty + i, n = n0 + tx;
    float v = (n < N_NODES) ? WA[(size_t)d*N_NODES + n] : 0.f;
    t[ty+i][tx] = v;
  }
  __syncthreads();
  #pragma unroll
  for (int i = 0; i < 32; i += 8){
    int n = n0 + ty + i, d = d0 + tx;
    if (n < N_NODES) WAt[(size_t)n*DIM + d] = t[tx][ty+i];
  }
}

// ---------------- CSR build ----------------
__global__ void k_hist(const int* __restrict__ row, int* __restrict__ deg){
  int e = blockIdx.x*256 + threadIdx.x;
  if (e < N_EDGES) atomicAdd(&deg[row[e]], 1);
}

__global__ __launch_bounds__(256) void k_scan1(const int* __restrict__ deg, int* __restrict__ bsum){
  __shared__ int s[256];
  int b = blockIdx.x, t = threadIdx.x;
  int base = b*2048 + t*8, v = 0;
  #pragma unroll
  for (int q = 0; q < 8; q++){ int i = base + q; if (i < N_NODES) v += deg[i]; }
  s[t] = v; __syncthreads();
  for (int off = 128; off > 0; off >>= 1){ if (t < off) s[t] += s[t+off]; __syncthreads(); }
  if (t == 0) bsum[b] = s[0];
}

__global__ void k_scan2(const int* __restrict__ bsum, int* __restrict__ boff, int* __restrict__ start){
  if (threadIdx.x == 0){
    int acc = 0;
    for (int b = 0; b < NB_SCAN; b++){ boff[b] = acc; acc += bsum[b]; }
    start[N_NODES] = acc;
  }
}

__global__ __launch_bounds__(256) void k_scan3(const int* __restrict__ deg, const int* __restrict__ boff,
                                               int* __restrict__ start, int* __restrict__ cursor){
  __shared__ int s[256];
  int b = blockIdx.x, t = threadIdx.x;
  int base = b*2048 + t*8;
  int loc[8]; int v = 0;
  #pragma unroll
  for (int q = 0; q < 8; q++){ int i = base + q; int d = (i < N_NODES) ? deg[i] : 0; loc[q] = v; v += d; }
  s[t] = v; __syncthreads();
  for (int off = 1; off < 256; off <<= 1){
    int tmp = (t >= off) ? s[t-off] : 0;
    __syncthreads();
    s[t] += tmp;
    __syncthreads();
  }
  int ex = s[t] - v + boff[b];   // exclusive prefix for this thread
  #pragma unroll
  for (int q = 0; q < 8; q++){
    int i = base + q;
    if (i < N_NODES){ int st = ex + loc[q]; start[i] = st; cursor[i] = st; }
  }
}

__global__ void k_scatter(const int* __restrict__ row, const int* __restrict__ col,
                          int* __restrict__ cursor, int* __restrict__ scol){
  int e = blockIdx.x*256 + threadIdx.x;
  if (e < N_EDGES){
    int r = row[e];
    int p = atomicAdd(&cursor[r], 1);
    scol[p] = col[e];
  }
}

// ---------------- xA[i] = sum_{e in CSR(i)} WAt[col[e]] + bA ----------------
// One 64-lane wave per node (no intra-wave divergence); float2 per lane = 512B/wave-instr.
__global__ __launch_bounds__(256) void k_gather(const int* __restrict__ start, const int* __restrict__ scol,
                                                const float* __restrict__ WAt, const float* __restrict__ bA,
                                                float* __restrict__ xA){
  int node = blockIdx.x*4 + (threadIdx.x >> 6);
  int t = threadIdx.x & 63;
  if (node >= N_NODES) return;
  int s0 = start[node], s1 = start[node+1];
  float2 acc = *reinterpret_cast<const float2*>(&bA[t*2]);
  int e = s0;
  // 2-deep manual pipeline on the index load to overlap L3 latency
  for (; e + 1 < s1; e += 2){
    int c0 = scol[e], c1 = scol[e+1];
    float2 w0 = *reinterpret_cast<const float2*>(&WAt[(size_t)c0*DIM + t*2]);
    float2 w1 = *reinterpret_cast<const float2*>(&WAt[(size_t)c1*DIM + t*2]);
    acc.x += w0.x + w1.x; acc.y += w0.y + w1.y;
  }
  if (e < s1){
    int c = scol[e];
    float2 w = *reinterpret_cast<const float2*>(&WAt[(size_t)c*DIM + t*2]);
    acc.x += w.x; acc.y += w.y;
  }
  *reinterpret_cast<float2*>(&xA[(size_t)node*DIM + t*2]) = acc;
}

// ---------------- fold weights: Ut[k][c]=W[c][k]+I, M=(W[:,128:]+I)@WX (transposed), W1t, b' ----------------
__global__ __launch_bounds__(256) void k_prep(const float* __restrict__ W, const float* __restrict__ WX,
                                              const float* __restrict__ bX, const float* __restrict__ bW,
                                              const float* __restrict__ W1,
                                              float* __restrict__ Ut, float* __restrict__ Mt,
                                              float* __restrict__ W1t, float* __restrict__ bp){
  int gid = blockIdx.x*256 + threadIdx.x;   // 0..16383
  int c = gid >> 7, d = gid & 127;
  float m = 0.f;
  for (int k = 0; k < 128; k++){
    float v = W[c*256 + 128 + k] + ((c == k) ? 1.f : 0.f);
    m += v * WX[k*128 + d];
  }
  Mt[d*128 + c]  = m;                                        // Mt[k][c] = M[c][k]
  Ut[d*128 + c]  = W[c*256 + d] + ((c == d) ? 1.f : 0.f);    // Ut[k][c] = U[c][k]
  W1t[d*128 + c] = W1[c*128 + d];                            // W1t[k][c] = W1[c][k]
  if (d == 0){
    float s = bW[c];
    for (int k = 0; k < 128; k++) s += (W[c*256 + 128 + k] + ((c == k) ? 1.f : 0.f)) * bX[k];
    bp[c] = s;
  }
}

// ---------------- fused: h=relu(U xA + M x + b'); h2=relu(W1 h + b1); BN partials ----------------
__global__ __launch_bounds__(256) void k_fused(const float* __restrict__ xA, const float* __restrict__ x,
                                               const float* __restrict__ Ut, const float* __restrict__ Mt,
                                               const float* __restrict__ bp, const float* __restrict__ W1t,
                                               const float* __restrict__ b1, float* __restrict__ h2,
                                               float* __restrict__ bnacc){
  __shared__ float xa[64*128];
  __shared__ float xx[64*128];
  __shared__ float wt[2*16*128];
  const int tid = threadIdx.x;
  const int n0 = blockIdx.x*64;

  for (int q = tid; q < 64*32; q += 256){
    int r = q >> 5, m = q & 31; int n = n0 + r;
    float4 va, vx;
    if (n < N_NODES){ va = ld4(&xA[(size_t)n*DIM + m*4]); vx = ld4(&x[(size_t)n*DIM + m*4]); }
    else { va = make_float4(0,0,0,0); vx = va; }
    st4(&xa[r*128 + m*4], va);
    st4(&xx[r*128 + m*4], vx);
  }
  const int tc = tid & 31, tr = tid >> 5;
  float acc[8][4];
  #pragma unroll
  for (int i = 0; i < 8; i++)
    #pragma unroll
    for (int j = 0; j < 4; j++) acc[i][j] = 0.f;

  // stage B: acc = U @ xA + M @ x
  for (int k0 = 0; k0 < 128; k0 += 16){
    __syncthreads();
    for (int q = tid; q < 512; q += 256){
      int kk = q >> 5, m = q & 31;
      st4(&wt[kk*128 + m*4],        ld4(&Ut[(k0+kk)*128 + m*4]));
      st4(&wt[2048 + kk*128 + m*4], ld4(&Mt[(k0+kk)*128 + m*4]));
    }
    __syncthreads();
    #pragma unroll
    for (int kk = 0; kk < 16; kk += 4){
      float ut[4][4], mt2[4][4];
      #pragma unroll
      for (int jj = 0; jj < 4; jj++){
        float4 u = ld4(&wt[(kk+jj)*128 + tc*4]);
        float4 w = ld4(&wt[2048 + (kk+jj)*128 + tc*4]);
        ut[jj][0] = u.x; ut[jj][1] = u.y; ut[jj][2] = u.z; ut[jj][3] = u.w;
        mt2[jj][0] = w.x; mt2[jj][1] = w.y; mt2[jj][2] = w.z; mt2[jj][3] = w.w;
      }
      #pragma unroll
      for (int i = 0; i < 8; i++){
        float4 av = ld4(&xa[(tr*8+i)*128 + k0 + kk]);
        float4 bv = ld4(&xx[(tr*8+i)*128 + k0 + kk]);
        float a_[4] = {av.x, av.y, av.z, av.w};
        float b_[4] = {bv.x, bv.y, bv.z, bv.w};
        #pragma unroll
        for (int j = 0; j < 4; j++){
          float s = acc[i][j];
          #pragma unroll
          for (int kkk = 0; kkk < 4; kkk++) s += a_[kkk]*ut[kkk][j] + b_[kkk]*mt2[kkk][j];
          acc[i][j] = s;
        }
      }
    }
  }

  // h = relu(acc + b'), stored into xa region
  __syncthreads();
  float4 bp4 = ld4(&bp[tc*4]);
  #pragma unroll
  for (int i = 0; i < 8; i++){
    float4 hv;
    hv.x = fmaxf(acc[i][0] + bp4.x, 0.f);
    hv.y = fmaxf(acc[i][1] + bp4.y, 0.f);
    hv.z = fmaxf(acc[i][2] + bp4.z, 0.f);
    hv.w = fmaxf(acc[i][3] + bp4.w, 0.f);
    st4(&xa[(tr*8+i)*128 + tc*4], hv);
  }
  __syncthreads();

  // stage C: acc2 = W1 @ h
  float acc2[8][4];
  #pragma unroll
  for (int i = 0; i < 8; i++)
    #pragma unroll
    for (int j = 0; j < 4; j++) acc2[i][j] = 0.f;

  for (int k0 = 0; k0 < 128; k0 += 16){
    __syncthreads();
    for (int q = tid; q < 512; q += 256){
      int kk = q >> 5, m = q & 31;
      st4(&wt[kk*128 + m*4], ld4(&W1t[(k0+kk)*128 + m*4]));
    }
    __syncthreads();
    #pragma unroll
    for (int kk = 0; kk < 16; kk += 4){
      float wt1[4][4];
      #pragma unroll
      for (int jj = 0; jj < 4; jj++){
        float4 u = ld4(&wt[(kk+jj)*128 + tc*4]);
        wt1[jj][0] = u.x; wt1[jj][1] = u.y; wt1[jj][2] = u.z; wt1[jj][3] = u.w;
      }
      #pragma unroll
      for (int i = 0; i < 8; i++){
        float4 av = ld4(&xa[(tr*8+i)*128 + k0 + kk]);
        float a_[4] = {av.x, av.y, av.z, av.w};
        #pragma unroll
        for (int j = 0; j < 4; j++){
          float s = acc2[i][j];
          #pragma unroll
          for (int kkk = 0; kkk < 4; kkk++) s += a_[kkk]*wt1[kkk][j];
          acc2[i][j] = s;
        }
      }
    }
  }

  // h2 = relu(acc2 + b1) -> global; BN partial sums
  float4 b14 = ld4(&b1[tc*4]);
  float ps[4] = {0,0,0,0}, pq[4] = {0,0,0,0};
  #pragma unroll
  for (int i = 0; i < 8; i++){
    int n = n0 + tr*8 + i;
    float4 hv;
    hv.x = fmaxf(acc2[i][0] + b14.x, 0.f);
    hv.y = fmaxf(acc2[i][1] + b14.y, 0.f);
    hv.z = fmaxf(acc2[i][2] + b14.z, 0.f);
    hv.w = fmaxf(acc2[i][3] + b14.w, 0.f);
    if (n < N_NODES){
      st4(&h2[(size_t)n*DIM + tc*4], hv);
      ps[0] += hv.x; ps[1] += hv.y; ps[2] += hv.z; ps[3] += hv.w;
      pq[0] += hv.x*hv.x; pq[1] += hv.y*hv.y; pq[2] += hv.z*hv.z; pq[3] += hv.w*hv.w;
    }
  }
  __syncthreads();
  float* red = xa;              // reuse LDS: [0..127]=sum, [128..255]=sumsq
  red[tid] = 0.f;
  __syncthreads();
  #pragma unroll
  for (int j = 0; j < 4; j++){
    atomicAdd(&red[tc*4 + j], ps[j]);
    atomicAdd(&red[128 + tc*4 + j], pq[j]);
  }
  __syncthreads();
  if (tid < 128){
    atomicAdd(&bnacc[tid],       red[tid]);
    atomicAdd(&bnacc[128 + tid], red[128 + tid]);
  }
}

// ---------------- fold BN into W2/b2 ----------------
__global__ void k_bnfold(const float* __restrict__ bnacc, const float* __restrict__ g1,
                         const float* __restrict__ beta1, const float* __restrict__ W2,
                         const float* __restrict__ b2, float* __restrict__ W2p, float* __restrict__ b2p){
  __shared__ float s[128], sh[128];
  int t = threadIdx.x;
  if (t < 128){
    float mu  = bnacc[t] * (1.f / N_NODES);
    float var = bnacc[128 + t] * (1.f / N_NODES) - mu*mu;
    float sc  = g1[t] * rsqrtf(var + 1e-5f);
    s[t] = sc; sh[t] = beta1[t] - mu*sc;
  }
  __syncthreads();
  for (int q = t; q < 64*128; q += 256){ int d = q & 127; W2p[q] = W2[q] * s[d]; }
  if (t < 64){
    float acc = b2[t];
    for (int d = 0; d < 128; d++) acc += W2[t*128 + d] * sh[d];
    b2p[t] = acc;
  }
}

// ---------------- out = h2 @ W2p.T + b2p ----------------
__global__ __launch_bounds__(256) void k_out(const float* __restrict__ h2, const float* __restrict__ W2p,
                                             const float* __restrict__ b2p, float* __restrict__ out){
  __shared__ float ht[64*132];
  __shared__ float w2[64*132];
  const int tid = threadIdx.x;
  const int n0 = blockIdx.x*64;
  for (int q = tid; q < 64*32; q += 256){
    int r = q >> 5, m = q & 31; int n = n0 + r;
    float4 hv = (n < N_NODES) ? ld4(&h2[(size_t)n*DIM + m*4]) : make_float4(0,0,0,0);
    st4(&ht[r*132 + m*4], hv);
    st4(&w2[r*132 + m*4], ld4(&W2p[r*128 + m*4]));
  }
  __syncthreads();
  const int tc = tid & 15, tr = tid >> 4;
  float acc[4][4];
  #pragma unroll
  for (int i = 0; i < 4; i++)
    #pragma unroll
    for (int j = 0; j < 4; j++) acc[i][j] = 0.f;
  #pragma unroll 8
  for (int k = 0; k < 128; k += 4){
    float hvv[4][4], wvv[4][4];
    #pragma unroll
    for (int i = 0; i < 4; i++){
      float4 v = ld4(&ht[(tr*4+i)*132 + k]);
      hvv[i][0] = v.x; hvv[i][1] = v.y; hvv[i][2] = v.z; hvv[i][3] = v.w;
    }
    #pragma unroll
    for (int j = 0; j < 4; j++){
      float4 v = ld4(&w2[(tc*4+j)*132 + k]);
      wvv[j][0] = v.x; wvv[j][1] = v.y; wvv[j][2] = v.z; wvv[j][3] = v.w;
    }
    #pragma unroll
    for (int i = 0; i < 4; i++)
      #pragma unroll
      for (int j = 0; j < 4; j++)
        #pragma unroll
        for (int kk = 0; kk < 4; kk++) acc[i][j] += hvv[i][kk]*wvv[j][kk];
  }
  float4 b4 = ld4(&b2p[tc*4]);
  #pragma unroll
  for (int i = 0; i < 4; i++){
    int n = n0 + tr*4 + i;
    if (n < N_NODES){
      float4 o; o.x = acc[i][0] + b4.x; o.y = acc[i][1] + b4.y; o.z = acc[i][2] + b4.z; o.w = acc[i][3] + b4.w;
      st4(&out[(size_t)n*C_OUT + tc*4], o);
    }
  }
}

extern "C" void kernel_launch(void* const* d_in, const int* in_sizes, int n_in,
                              void* d_out, int out_size, void* d_ws, size_t ws_size,
                              hipStream_t stream){
  (void)in_sizes; (void)n_in; (void)out_size; (void)ws_size;
  const float* x     = (const float*)d_in[0];
  const int*   row   = (const int*)  d_in[1];
  const int*   col   = (const int*)  d_in[2];
  const float* WA    = (const float*)d_in[3];
  const float* bA    = (const float*)d_in[4];
  const float* WX    = (const float*)d_in[5];
  const float* bX    = (const float*)d_in[6];
  const float* W     = (const float*)d_in[7];
  const float* bW    = (const float*)d_in[8];
  const float* W1    = (const float*)d_in[9];
  const float* b1    = (const float*)d_in[10];
  const float* g1    = (const float*)d_in[11];
  const float* beta1 = (const float*)d_in[12];
  const float* W2    = (const float*)d_in[13];
  const float* b2    = (const float*)d_in[14];
  float* out = (float*)d_out;

  char* w = (char*)d_ws;
  size_t off = 0;
  auto alloc = [&](size_t bytes) -> void* {
    void* p = (void*)(w + off);
    off += (bytes + 511) & ~(size_t)511;
    return p;
  };
  float* WAt   = (float*)alloc((size_t)N_NODES*DIM*4);   // aliased as h2 after gather
  float* h2    = WAt;
  float* xA    = (float*)alloc((size_t)N_NODES*DIM*4);
  int*   scol  = (int*)  alloc((size_t)N_EDGES*4);
  int*   deg   = (int*)  alloc((size_t)N_NODES*4);
  int*   start = (int*)  alloc((size_t)(N_NODES+1)*4);
  int*   cursor= (int*)  alloc((size_t)N_NODES*4);
  int*   bsum  = (int*)  alloc(NB_SCAN*4);
  int*   boff  = (int*)  alloc(NB_SCAN*4);
  float* Ut    = (float*)alloc(128*128*4);
  float* Mt    = (float*)alloc(128*128*4);
  float* W1t   = (float*)alloc(128*128*4);
  float* bp    = (float*)alloc(128*4);
  float* bnacc = (float*)alloc(256*4);
  float* W2p   = (float*)alloc(64*128*4);
  float* b2p   = (float*)alloc(64*4);

  hipMemsetAsync(deg, 0, (size_t)N_NODES*4, stream);
  hipMemsetAsync(bnacc, 0, 256*4, stream);

  k_transpose<<<dim3(3125, 4), 256, 0, stream>>>(WA, WAt);
  k_hist<<<(N_EDGES+255)/256, 256, 0, stream>>>(row, deg);
  k_scan1<<<NB_SCAN, 256, 0, stream>>>(deg, bsum);
  k_scan2<<<1, 64, 0, stream>>>(bsum, boff, start);
  k_scan3<<<NB_SCAN, 256, 0, stream>>>(deg, boff, start, cursor);
  k_scatter<<<(N_EDGES+255)/256, 256, 0, stream>>>(row, col, cursor, scol);
  k_gather<<<(N_NODES+3)/4, 256, 0, stream>>>(start, scol, WAt, bA, xA);
  k_prep<<<64, 256, 0, stream>>>(W, WX, bX, bW, W1, Ut, Mt, W1t, bp);
  k_fused<<<(N_NODES+63)/64, 256, 0, stream>>>(xA, x, Ut, Mt, bp, W1t, b1, h2, bnacc);
  k_bnfold<<<1, 256, 0, stream>>>(bnacc, g1, beta1, W2, b2, W2p, b2p);
  k_out<<<(N_NODES+63)/64, 256, 0, stream>>>(h2, W2p, b2p, out);
}

// Round 3
// 581.679 us; speedup vs baseline: 1.4915x; 1.4915x over previous
//
#include <hip/hip_runtime.h>
#include <hip/hip_bf16.h>

#define N_NODES 100000
#define N_EDGES 1600000
#define DIM 128
#define C_OUT 64
#define NB_SCAN 49   // ceil(N_NODES / 2048)

typedef float f32x4 __attribute__((ext_vector_type(4)));
typedef __bf16 bf16x8 __attribute__((ext_vector_type(8)));

#define MFMA(a,b,c) __builtin_amdgcn_mfma_f32_16x16x32_bf16((a),(b),(c),0,0,0)

static __device__ __forceinline__ float4 ld4(const float* p){ return *reinterpret_cast<const float4*>(p); }
static __device__ __forceinline__ void st4(float* p, float4 v){ *reinterpret_cast<float4*>(p) = v; }
static __device__ __forceinline__ f32x4 ld4v(const float* p){ return *reinterpret_cast<const f32x4*>(p); }

// build hi/lo bf16x8 frags from two f32x4 (elems 0-3 from a0, 4-7 from a1)
static __device__ __forceinline__ void split8(f32x4 a0, f32x4 a1, bf16x8& hi, bf16x8& lo){
  #pragma unroll
  for (int j = 0; j < 4; j++){
    float v = a0[j]; __bf16 h = (__bf16)v; hi[j] = h; lo[j] = (__bf16)(v - (float)h);
  }
  #pragma unroll
  for (int j = 0; j < 4; j++){
    float v = a1[j]; __bf16 h = (__bf16)v; hi[4+j] = h; lo[4+j] = (__bf16)(v - (float)h);
  }
}

// ---------------- transpose WA [128][N] -> WAtb [N][128] (bf16) ----------------
__global__ __launch_bounds__(256) void k_transpose(const float* __restrict__ WA, __bf16* __restrict__ WAtb){
  __shared__ float t[32][33];
  int n0 = blockIdx.x*32, d0 = blockIdx.y*32;
  int tx = threadIdx.x & 31, ty = threadIdx.x >> 5;   // 32 x 8
  #pragma unroll
  for (int i = 0; i < 32; i += 8){
    int d = d0 + ty + i, n = n0 + tx;
    t[ty+i][tx] = (n < N_NODES) ? WA[(size_t)d*N_NODES + n] : 0.f;
  }
  __syncthreads();
  #pragma unroll
  for (int i = 0; i < 32; i += 8){
    int n = n0 + ty + i, d = d0 + tx;
    if (n < N_NODES) WAtb[(size_t)n*DIM + d] = (__bf16)t[tx][ty+i];
  }
}

// ---------------- CSR build ----------------
__global__ void k_hist(const int* __restrict__ row, int* __restrict__ deg){
  int e = blockIdx.x*256 + threadIdx.x;
  if (e < N_EDGES) atomicAdd(&deg[row[e]], 1);
}

__global__ __launch_bounds__(256) void k_scan1(const int* __restrict__ deg, int* __restrict__ bsum){
  __shared__ int s[256];
  int b = blockIdx.x, t = threadIdx.x;
  int base = b*2048 + t*8, v = 0;
  #pragma unroll
  for (int q = 0; q < 8; q++){ int i = base + q; if (i < N_NODES) v += deg[i]; }
  s[t] = v; __syncthreads();
  for (int off = 128; off > 0; off >>= 1){ if (t < off) s[t] += s[t+off]; __syncthreads(); }
  if (t == 0) bsum[b] = s[0];
}

__global__ void k_scan2(const int* __restrict__ bsum, int* __restrict__ boff, int* __restrict__ start){
  if (threadIdx.x == 0){
    int acc = 0;
    for (int b = 0; b < NB_SCAN; b++){ boff[b] = acc; acc += bsum[b]; }
    start[N_NODES] = acc;
  }
}

__global__ __launch_bounds__(256) void k_scan3(const int* __restrict__ deg, const int* __restrict__ boff,
                                               int* __restrict__ start, int* __restrict__ cursor){
  __shared__ int s[256];
  int b = blockIdx.x, t = threadIdx.x;
  int base = b*2048 + t*8;
  int loc[8]; int v = 0;
  #pragma unroll
  for (int q = 0; q < 8; q++){ int i = base + q; int d = (i < N_NODES) ? deg[i] : 0; loc[q] = v; v += d; }
  s[t] = v; __syncthreads();
  for (int off = 1; off < 256; off <<= 1){
    int tmp = (t >= off) ? s[t-off] : 0;
    __syncthreads();
    s[t] += tmp;
    __syncthreads();
  }
  int ex = s[t] - v + boff[b];
  #pragma unroll
  for (int q = 0; q < 8; q++){
    int i = base + q;
    if (i < N_NODES){ int st = ex + loc[q]; start[i] = st; cursor[i] = st; }
  }
}

__global__ void k_scatter(const int* __restrict__ row, const int* __restrict__ col,
                          int* __restrict__ cursor, int* __restrict__ scol){
  int e = blockIdx.x*256 + threadIdx.x;
  if (e < N_EDGES){
    int r = row[e];
    int p = atomicAdd(&cursor[r], 1);
    scol[p] = col[e];
  }
}

// ---------------- xA[i] = sum_{e in CSR(i)} WAtb[col[e]] + bA (bf16 in, f32 out) ----------------
__global__ __launch_bounds__(256) void k_gather(const int* __restrict__ start, const int* __restrict__ scol,
                                                const __bf16* __restrict__ WAtb, const float* __restrict__ bA,
                                                float* __restrict__ xA){
  int node = blockIdx.x*4 + (threadIdx.x >> 6);
  int t = threadIdx.x & 63;
  if (node >= N_NODES) return;
  int s0 = start[node], s1 = start[node+1];
  float2 acc = *reinterpret_cast<const float2*>(&bA[t*2]);
  int e = s0;
  for (; e + 1 < s1; e += 2){
    int c0 = scol[e], c1 = scol[e+1];
    unsigned v0 = *reinterpret_cast<const unsigned*>(WAtb + (size_t)c0*DIM + t*2);
    unsigned v1 = *reinterpret_cast<const unsigned*>(WAtb + (size_t)c1*DIM + t*2);
    acc.x += __builtin_bit_cast(float, v0 << 16) + __builtin_bit_cast(float, v1 << 16);
    acc.y += __builtin_bit_cast(float, v0 & 0xFFFF0000u) + __builtin_bit_cast(float, v1 & 0xFFFF0000u);
  }
  if (e < s1){
    unsigned v0 = *reinterpret_cast<const unsigned*>(WAtb + (size_t)scol[e]*DIM + t*2);
    acc.x += __builtin_bit_cast(float, v0 << 16);
    acc.y += __builtin_bit_cast(float, v0 & 0xFFFF0000u);
  }
  *reinterpret_cast<float2*>(&xA[(size_t)node*DIM + t*2]) = acc;
}

// ---------------- fold weights into bf16 hi/lo MFMA B-fragment buffers ----------------
// frag elem j at lane l holds B[k][n]: n = 16*ct + (l&15), k = 32*kb + (j>=4)*16 + 4*(l>>4) + (j&3)
__global__ __launch_bounds__(256) void k_prep(const float* __restrict__ W, const float* __restrict__ WX,
                                              const float* __restrict__ bX, const float* __restrict__ bW,
                                              const float* __restrict__ W1,
                                              __bf16* __restrict__ Ufh, __bf16* __restrict__ Ufl,
                                              __bf16* __restrict__ Mfh, __bf16* __restrict__ Mfl,
                                              __bf16* __restrict__ W1fh, __bf16* __restrict__ W1fl,
                                              float* __restrict__ bp){
  int gid = blockIdx.x*256 + threadIdx.x;   // 16384 = 128c x 128k
  int c = gid >> 7, k = gid & 127;
  float mv = 0.f;
  for (int d = 0; d < 128; d++)
    mv += (W[c*256 + 128 + d] + ((c==d)?1.f:0.f)) * WX[d*128 + k];
  float uv  = W[c*256 + k] + ((c==k)?1.f:0.f);
  float w1v = W1[c*128 + k];
  int ct = c >> 4, nl = c & 15;
  int kb = k >> 5, k5 = k & 31;
  int j  = ((k5>>4)<<2) | (k5 & 3);
  int gg = (k5 >> 2) & 3;
  int idx = ((kb*8 + ct)*64 + gg*16 + nl)*8 + j;
  __bf16 h;
  h = (__bf16)uv;  Ufh[idx]  = h; Ufl[idx]  = (__bf16)(uv  - (float)h);
  h = (__bf16)mv;  Mfh[idx]  = h; Mfl[idx]  = (__bf16)(mv  - (float)h);
  h = (__bf16)w1v; W1fh[idx] = h; W1fl[idx] = (__bf16)(w1v - (float)h);
  if (k == 0){
    float s = bW[c];
    for (int d = 0; d < 128; d++) s += (W[c*256+128+d] + ((c==d)?1.f:0.f)) * bX[d];
    bp[c] = s;
  }
}

// ---------------- fused MFMA: h=relu(xA@Ut + x@Mt + b'); h2=relu(h@W1t + b1); BN partials ----------------
__global__ __launch_bounds__(256) void k_fused(const float* __restrict__ xA, const float* __restrict__ x,
    const __bf16* __restrict__ Ufh, const __bf16* __restrict__ Ufl,
    const __bf16* __restrict__ Mfh, const __bf16* __restrict__ Mfl,
    const __bf16* __restrict__ W1fh, const __bf16* __restrict__ W1fl,
    const float* __restrict__ bp, const float* __restrict__ b1,
    __bf16* __restrict__ h2fh, __bf16* __restrict__ h2fl,
    float* __restrict__ bnacc){
  __shared__ float hbuf[4][16*132];     // per-wave h tile, stride 132 (uniform banks)
  __shared__ float red[256];
  const int tid = threadIdx.x;
  const int w = tid >> 6, l = tid & 63;
  const int g = l >> 4, m = l & 15;
  const int n0 = blockIdx.x*64;
  const int rowbase = n0 + 16*w;
  red[tid] = 0.f;

  int row = rowbase + m;
  int rowc = row < N_NODES ? row : 0;   // clamp addr (results masked later)
  const float* pA = xA + (size_t)rowc*DIM;
  const float* pX = x  + (size_t)rowc*DIM;
  float* hb = hbuf[w];

  f32x4 acc[8];
  #pragma unroll
  for (int ct = 0; ct < 8; ct++) acc[ct] = (f32x4){0.f,0.f,0.f,0.f};

  // stage B: acc = xA@Ut + x@Mt  (bf16x3)
  #pragma unroll
  for (int kb = 0; kb < 4; kb++){
    int k0 = kb*32 + 4*g;
    bf16x8 Ah, Al, Xh, Xl;
    split8(ld4v(pA + k0), ld4v(pA + k0 + 16), Ah, Al);
    split8(ld4v(pX + k0), ld4v(pX + k0 + 16), Xh, Xl);
    #pragma unroll
    for (int ct = 0; ct < 8; ct++){
      int fo = ((kb*8 + ct)*64 + l)*8;
      bf16x8 uh = *reinterpret_cast<const bf16x8*>(Ufh + fo);
      bf16x8 ul = *reinterpret_cast<const bf16x8*>(Ufl + fo);
      bf16x8 mh = *reinterpret_cast<const bf16x8*>(Mfh + fo);
      bf16x8 ml = *reinterpret_cast<const bf16x8*>(Mfl + fo);
      f32x4 c = acc[ct];
      c = MFMA(Al, uh, c); c = MFMA(Ah, ul, c); c = MFMA(Ah, uh, c);
      c = MFMA(Xl, mh, c); c = MFMA(Xh, ml, c); c = MFMA(Xh, mh, c);
      acc[ct] = c;
    }
  }
  // epilogue B: h = relu(acc + b') -> hbuf (D-frag: row=4g+r, col=16ct+m)
  #pragma unroll
  for (int ct = 0; ct < 8; ct++){
    float bpv = bp[16*ct + m];
    #pragma unroll
    for (int r = 0; r < 4; r++)
      hb[(4*g + r)*132 + 16*ct + m] = fmaxf(acc[ct][r] + bpv, 0.f);
  }
  __syncthreads();

  // stage C: acc2 = h@W1t (A-frags from hbuf row m)
  f32x4 acc2[8];
  #pragma unroll
  for (int ct = 0; ct < 8; ct++) acc2[ct] = (f32x4){0.f,0.f,0.f,0.f};
  #pragma unroll
  for (int kb = 0; kb < 4; kb++){
    int k0 = kb*32 + 4*g;
    bf16x8 Hh, Hl;
    split8(ld4v(&hb[m*132 + k0]), ld4v(&hb[m*132 + k0 + 16]), Hh, Hl);
    #pragma unroll
    for (int ct = 0; ct < 8; ct++){
      int fo = ((kb*8 + ct)*64 + l)*8;
      bf16x8 wh = *reinterpret_cast<const bf16x8*>(W1fh + fo);
      bf16x8 wl = *reinterpret_cast<const bf16x8*>(W1fl + fo);
      f32x4 c = acc2[ct];
      c = MFMA(Hl, wh, c); c = MFMA(Hh, wl, c); c = MFMA(Hh, wh, c);
      acc2[ct] = c;
    }
  }
  __syncthreads();   // all stage-C reads done before hbuf overwrite

  // epilogue C: h2 = relu(acc2 + b1) -> hbuf; BN partial sums
  const bool allvalid = (n0 + 64 <= N_NODES);
  #pragma unroll
  for (int ct = 0; ct < 8; ct++){
    float b1v = b1[16*ct + m];
    float s = 0.f, q = 0.f;
    #pragma unroll
    for (int r = 0; r < 4; r++){
      float hv = fmaxf(acc2[ct][r] + b1v, 0.f);
      hb[(4*g + r)*132 + 16*ct + m] = hv;
      if (allvalid || (rowbase + 4*g + r) < N_NODES){ s += hv; q += hv*hv; }
    }
    s += __shfl_xor(s, 16); s += __shfl_xor(s, 32);
    q += __shfl_xor(q, 16); q += __shfl_xor(q, 32);
    if (l < 16){ atomicAdd(&red[16*ct + m], s); atomicAdd(&red[128 + 16*ct + m], q); }
  }
  __syncthreads();

  // store h2 in bf16 hi/lo A-fragment layout for k_out
  int rowtile = blockIdx.x*4 + w;
  #pragma unroll
  for (int kb = 0; kb < 4; kb++){
    int k0 = kb*32 + 4*g;
    bf16x8 Hh, Hl;
    split8(ld4v(&hb[m*132 + k0]), ld4v(&hb[m*132 + k0 + 16]), Hh, Hl);
    size_t fo = ((size_t)(rowtile*4 + kb)*64 + l)*8;
    *reinterpret_cast<bf16x8*>(h2fh + fo) = Hh;
    *reinterpret_cast<bf16x8*>(h2fl + fo) = Hl;
  }
  if (tid < 128){
    atomicAdd(&bnacc[tid],       red[tid]);
    atomicAdd(&bnacc[128 + tid], red[128 + tid]);
  }
}

// ---------------- fold BN into W2 (frag layout) / b2 ----------------
__global__ void k_bnfold(const float* __restrict__ bnacc, const float* __restrict__ g1,
                         const float* __restrict__ beta1, const float* __restrict__ W2,
                         const float* __restrict__ b2,
                         __bf16* __restrict__ W2fh, __bf16* __restrict__ W2fl, float* __restrict__ b2p){
  __shared__ float s[128], sh[128];
  int t = threadIdx.x;
  if (t < 128){
    float mu  = bnacc[t] * (1.f / N_NODES);
    float var = bnacc[128 + t] * (1.f / N_NODES) - mu*mu;
    float sc  = g1[t] * rsqrtf(var + 1e-5f);
    s[t] = sc; sh[t] = beta1[t] - mu*sc;
  }
  __syncthreads();
  for (int q = t; q < 64*128; q += 256){
    int c = q >> 7, k = q & 127;
    float val = W2[q] * s[k];
    int ct = c >> 4, nl = c & 15;
    int kb = k >> 5, k5 = k & 31;
    int j  = ((k5>>4)<<2) | (k5 & 3);
    int gg = (k5 >> 2) & 3;
    int idx = ((kb*4 + ct)*64 + gg*16 + nl)*8 + j;
    __bf16 h = (__bf16)val; W2fh[idx] = h; W2fl[idx] = (__bf16)(val - (float)h);
  }
  if (t < 64){
    float a = b2[t];
    for (int d = 0; d < 128; d++) a += W2[t*128 + d] * sh[d];
    b2p[t] = a;
  }
}

// ---------------- out = h2n @ W2p^T + b2p (MFMA bf16x3) ----------------
__global__ __launch_bounds__(256) void k_out(const __bf16* __restrict__ h2fh, const __bf16* __restrict__ h2fl,
                                             const __bf16* __restrict__ W2fh, const __bf16* __restrict__ W2fl,
                                             const float* __restrict__ b2p, float* __restrict__ out){
  const int tid = threadIdx.x;
  const int w = tid >> 6, l = tid & 63;
  const int g = l >> 4, m = l & 15;
  const int rowtile = blockIdx.x*4 + w;
  f32x4 acc[4];
  #pragma unroll
  for (int ct = 0; ct < 4; ct++) acc[ct] = (f32x4){0.f,0.f,0.f,0.f};
  #pragma unroll
  for (int kb = 0; kb < 4; kb++){
    size_t ao = ((size_t)(rowtile*4 + kb)*64 + l)*8;
    bf16x8 ah = *reinterpret_cast<const bf16x8*>(h2fh + ao);
    bf16x8 al = *reinterpret_cast<const bf16x8*>(h2fl + ao);
    #pragma unroll
    for (int ct = 0; ct < 4; ct++){
      int fo = ((kb*4 + ct)*64 + l)*8;
      bf16x8 wh = *reinterpret_cast<const bf16x8*>(W2fh + fo);
      bf16x8 wl = *reinterpret_cast<const bf16x8*>(W2fl + fo);
      f32x4 c = acc[ct];
      c = MFMA(al, wh, c); c = MFMA(ah, wl, c); c = MFMA(ah, wh, c);
      acc[ct] = c;
    }
  }
  int rowb = blockIdx.x*64 + 16*w + 4*g;
  #pragma unroll
  for (int ct = 0; ct < 4; ct++){
    float bv = b2p[16*ct + m];
    #pragma unroll
    for (int r = 0; r < 4; r++){
      int row2 = rowb + r;
      if (row2 < N_NODES) out[(size_t)row2*C_OUT + 16*ct + m] = acc[ct][r] + bv;
    }
  }
}

extern "C" void kernel_launch(void* const* d_in, const int* in_sizes, int n_in,
                              void* d_out, int out_size, void* d_ws, size_t ws_size,
                              hipStream_t stream){
  (void)in_sizes; (void)n_in; (void)out_size; (void)ws_size;
  const float* x     = (const float*)d_in[0];
  const int*   row   = (const int*)  d_in[1];
  const int*   col   = (const int*)  d_in[2];
  const float* WA    = (const float*)d_in[3];
  const float* bA    = (const float*)d_in[4];
  const float* WX    = (const float*)d_in[5];
  const float* bX    = (const float*)d_in[6];
  const float* W     = (const float*)d_in[7];
  const float* bW    = (const float*)d_in[8];
  const float* W1    = (const float*)d_in[9];
  const float* b1    = (const float*)d_in[10];
  const float* g1    = (const float*)d_in[11];
  const float* beta1 = (const float*)d_in[12];
  const float* W2    = (const float*)d_in[13];
  const float* b2    = (const float*)d_in[14];
  float* out = (float*)d_out;

  char* wsb = (char*)d_ws;
  size_t off = 0;
  auto alloc = [&](size_t bytes) -> void* {
    void* p = (void*)(wsb + off);
    off += (bytes + 511) & ~(size_t)511;
    return p;
  };
  const size_t NROWTILES = 1563*4;                     // 6252
  const size_t FRAG_H2   = NROWTILES*4*64*8;           // elems
  __bf16* WAtb = (__bf16*)alloc(FRAG_H2*2);            // 25.6MB; aliased as h2fh
  __bf16* h2fh = WAtb;
  float*  xA   = (float*)alloc((size_t)(N_NODES+32)*DIM*4);
  __bf16* h2fl = (__bf16*)alloc(FRAG_H2*2);
  int*   scol  = (int*)  alloc((size_t)N_EDGES*4);
  int*   deg   = (int*)  alloc((size_t)N_NODES*4);
  int*   start = (int*)  alloc((size_t)(N_NODES+1)*4);
  int*   cursor= (int*)  alloc((size_t)N_NODES*4);
  int*   bsum  = (int*)  alloc(NB_SCAN*4);
  int*   boff  = (int*)  alloc(NB_SCAN*4);
  __bf16* Ufh  = (__bf16*)alloc(4*8*64*8*2);
  __bf16* Ufl  = (__bf16*)alloc(4*8*64*8*2);
  __bf16* Mfh  = (__bf16*)alloc(4*8*64*8*2);
  __bf16* Mfl  = (__bf16*)alloc(4*8*64*8*2);
  __bf16* W1fh = (__bf16*)alloc(4*8*64*8*2);
  __bf16* W1fl = (__bf16*)alloc(4*8*64*8*2);
  __bf16* W2fh = (__bf16*)alloc(4*4*64*8*2);
  __bf16* W2fl = (__bf16*)alloc(4*4*64*8*2);
  float* bp    = (float*)alloc(128*4);
  float* bnacc = (float*)alloc(256*4);
  float* b2p   = (float*)alloc(64*4);

  hipMemsetAsync(deg, 0, (size_t)N_NODES*4, stream);
  hipMemsetAsync(bnacc, 0, 256*4, stream);

  k_transpose<<<dim3(3125, 4), 256, 0, stream>>>(WA, WAtb);
  k_hist<<<(N_EDGES+255)/256, 256, 0, stream>>>(row, deg);
  k_scan1<<<NB_SCAN, 256, 0, stream>>>(deg, bsum);
  k_scan2<<<1, 64, 0, stream>>>(bsum, boff, start);
  k_scan3<<<NB_SCAN, 256, 0, stream>>>(deg, boff, start, cursor);
  k_scatter<<<(N_EDGES+255)/256, 256, 0, stream>>>(row, col, cursor, scol);
  k_gather<<<(N_NODES+3)/4, 256, 0, stream>>>(start, scol, WAtb, bA, xA);
  k_prep<<<64, 256, 0, stream>>>(W, WX, bX, bW, W1, Ufh, Ufl, Mfh, Mfl, W1fh, W1fl, bp);
  k_fused<<<1563, 256, 0, stream>>>(xA, x, Ufh, Ufl, Mfh, Mfl, W1fh, W1fl, bp, b1, h2fh, h2fl, bnacc);
  k_bnfold<<<1, 256, 0, stream>>>(bnacc, g1, beta1, W2, b2, W2fh, W2fl, b2p);
  k_out<<<1563, 256, 0, stream>>>(h2fh, h2fl, W2fh, W2fl, b2p, out);
}